// Round 6
// baseline (1213.632 us; speedup 1.0000x reference)
//
#include <hip/hip_runtime.h>
#include <hip/hip_bf16.h>
#include <math.h>

// BernNet: h = relu(x@W1+b1)@W2+b2 ; out = sum_m c_m A^m h (Horner) ; log_softmax
// A = D^-1/2 Adj D^-1/2 (deg from src, scatter by dst). CSR(dst) built per launch
// via bucketed counting sort; deg via a parallel src-bucket byte sort (NO per-edge
// global atomics anywhere -- they caused ~50B/edge HBM write amplification).

#define NFEAT 512
#define HIDDEN 128
#define NCLASS 64
#define KORD 10
#define MAXBUCK 1600   // LDS histogram capacity (N <= 102400)
#define CH 8192        // edges per block in bucket passes (391 blocks)

typedef unsigned short ushort_t;
typedef __attribute__((ext_vector_type(8))) short short8;
typedef __attribute__((ext_vector_type(4))) float f32x4;
typedef __attribute__((ext_vector_type(4))) unsigned short us4v;

static __device__ __forceinline__ float bf2f(ushort_t u) {
    return __uint_as_float(((unsigned)u) << 16);
}
static __device__ __forceinline__ ushort_t f2bf(float f) {
    __hip_bfloat16 h = __float2bfloat16(f);
    return *reinterpret_cast<ushort_t*>(&h);
}
static __device__ __forceinline__ short8 pack8(float4 a, float4 b) {
    short8 r;
    r[0] = (short)f2bf(a.x); r[1] = (short)f2bf(a.y);
    r[2] = (short)f2bf(a.z); r[3] = (short)f2bf(a.w);
    r[4] = (short)f2bf(b.x); r[5] = (short)f2bf(b.y);
    r[6] = (short)f2bf(b.z); r[7] = (short)f2bf(b.w);
    return r;
}

// ---------------- graph build: bucketed counting sort ----------------

// phase 0: dual bucket histogram (dst>>6 and src>>6), LDS-aggregated
__global__ __launch_bounds__(256) void p0_hist(const int* __restrict__ src,
                                               const int* __restrict__ dst,
                                               int* __restrict__ bhist,  // [2*MAXBUCK]
                                               int E, int nbuck) {
    __shared__ int hd[MAXBUCK];
    __shared__ int hs[MAXBUCK];
    for (int i = threadIdx.x; i < nbuck; i += 256) { hd[i] = 0; hs[i] = 0; }
    __syncthreads();
    int base = blockIdx.x * CH;
    int lim = min(base + CH, E);
    for (int e = base + threadIdx.x; e < lim; e += 256) {
        atomicAdd(&hd[dst[e] >> 6], 1);
        atomicAdd(&hs[src[e] >> 6], 1);
    }
    __syncthreads();
    for (int i = threadIdx.x; i < nbuck; i += 256) {
        int v = hd[i];
        if (v) atomicAdd(&bhist[i], v);
        int w = hs[i];
        if (w) atomicAdd(&bhist[MAXBUCK + i], w);
    }
}

// exclusive scans: bhist[0..]->bstart/gpos, bhist[MAXBUCK..]->sstart/spos
__global__ __launch_bounds__(256) void p_scan(const int* __restrict__ bhist,
                                              int* __restrict__ bstart,
                                              int* __restrict__ gpos,
                                              int* __restrict__ sstart,
                                              int* __restrict__ spos, int nbuck,
                                              int* __restrict__ row_ptr, int N, int E) {
    __shared__ int ws[4];
    __shared__ int carry;
    int t = threadIdx.x, lane = t & 63, w = t >> 6;
    #pragma unroll
    for (int pass = 0; pass < 2; ++pass) {
        const int* in = bhist + pass * MAXBUCK;
        int* o1 = pass ? sstart : bstart;
        int* o2 = pass ? spos : gpos;
        if (t == 0) carry = 0;
        __syncthreads();
        for (int base = 0; base < nbuck; base += 256) {
            int i = base + t;
            int v = (i < nbuck) ? in[i] : 0;
            int s = v;
            #pragma unroll
            for (int off = 1; off < 64; off <<= 1) {
                int u = __shfl_up(s, off);
                if (lane >= off) s += u;
            }
            if (lane == 63) ws[w] = s;
            __syncthreads();
            int pre = 0;
            #pragma unroll
            for (int j = 0; j < 4; ++j)
                if (j < w) pre += ws[j];
            int excl = carry + pre + s - v;
            if (i < nbuck) {
                o1[i] = excl;
                o2[i] = excl;
            }
            __syncthreads();
            if (t == 255) carry += pre + s;
            __syncthreads();
        }
        if (t == 0) o1[nbuck] = E;
        __syncthreads();
    }
    if (t == 0) row_ptr[N] = E;
}

// phase 1: scatter packed (src | dstlow<<17) into dst-bucket regions AND
// (src&63) bytes into src-bucket regions. No global atomics per edge.
__global__ __launch_bounds__(256) void p1_scatter(const int* __restrict__ src,
                                                  const int* __restrict__ dst,
                                                  int* __restrict__ gpos,
                                                  int* __restrict__ spos,
                                                  int* __restrict__ buf,
                                                  unsigned char* __restrict__ sbuf,
                                                  int E, int nbuck) {
    __shared__ int hd[MAXBUCK];
    __shared__ int bd[MAXBUCK];
    __shared__ int hs[MAXBUCK];
    __shared__ int bs[MAXBUCK];
    for (int i = threadIdx.x; i < nbuck; i += 256) { hd[i] = 0; hs[i] = 0; }
    __syncthreads();
    int base = blockIdx.x * CH;
    int lim = min(base + CH, E);
    for (int e = base + threadIdx.x; e < lim; e += 256) {
        atomicAdd(&hd[dst[e] >> 6], 1);
        atomicAdd(&hs[src[e] >> 6], 1);
    }
    __syncthreads();
    for (int i = threadIdx.x; i < nbuck; i += 256) {
        int v = hd[i];
        bd[i] = v ? atomicAdd(&gpos[i], v) : 0;
        hd[i] = 0;
        int u = hs[i];
        bs[i] = u ? atomicAdd(&spos[i], u) : 0;
        hs[i] = 0;
    }
    __syncthreads();
    for (int e = base + threadIdx.x; e < lim; e += 256) {
        int d = dst[e], s = src[e];
        int bk = d >> 6;
        int off = atomicAdd(&hd[bk], 1);
        buf[bd[bk] + off] = s | ((d & 63) << 17);
        int sk = s >> 6;
        int off2 = atomicAdd(&hs[sk], 1);
        sbuf[bs[sk] + off2] = (unsigned char)(s & 63);
    }
}

// phase 2: per-dst-bucket grouping into final CSR + row_ptr (all-LDS)
__global__ __launch_bounds__(256) void p2_group(const int* __restrict__ buf,
                                                const int* __restrict__ bstart,
                                                int* __restrict__ csr,
                                                int* __restrict__ row_ptr, int N) {
    int bk = blockIdx.x;
    int s0 = bstart[bk], s1 = bstart[bk + 1];
    __shared__ int cnt[64];
    __shared__ int pos[64];
    int t = threadIdx.x;
    if (t < 64) cnt[t] = 0;
    __syncthreads();
    for (int i = s0 + t; i < s1; i += 256) atomicAdd(&cnt[buf[i] >> 17], 1);
    __syncthreads();
    if (t < 64) {
        int v = cnt[t], s = v;
        #pragma unroll
        for (int off = 1; off < 64; off <<= 1) {
            int u = __shfl_up(s, off);
            if (t >= off) s += u;
        }
        int excl = s - v;
        int node = bk * 64 + t;
        if (node < N) row_ptr[node] = s0 + excl;
        pos[t] = s0 + excl;
    }
    __syncthreads();
    for (int i = s0 + t; i < s1; i += 256) {
        int p = buf[i];
        int off = atomicAdd(&pos[p >> 17], 1);
        csr[off] = p & 0x1FFFF;
    }
}

// phase 2b: per-src-bucket degree count -> dinv (fuses k_dinv)
__global__ __launch_bounds__(256) void p2b_deg(const unsigned char* __restrict__ sbuf,
                                               const int* __restrict__ sstart,
                                               float* __restrict__ dinv, int N) {
    int bk = blockIdx.x;
    int s0 = sstart[bk], s1 = sstart[bk + 1];
    __shared__ int cnt[64];
    int t = threadIdx.x;
    if (t < 64) cnt[t] = 0;
    __syncthreads();
    for (int i = s0 + t; i < s1; i += 256) atomicAdd(&cnt[sbuf[i]], 1);
    __syncthreads();
    if (t < 64) {
        int node = bk * 64 + t;
        if (node < N) {
            int d = cnt[t];
            dinv[node] = (d > 0) ? rsqrtf((float)d) : 0.0f;
        }
    }
}

// ---------------- Bernstein coefficients ----------------

__global__ void k_coef(const float* __restrict__ temp, float* __restrict__ c,
                       float* __restrict__ temp_out) {
    if (threadIdx.x != 0 || blockIdx.x != 0) return;
    float T[KORD + 1];
    #pragma unroll
    for (int j = 0; j <= KORD; ++j) {
        T[j] = fmaxf(temp[j], 0.0f);
        temp_out[j] = T[j];
    }
    float binom[KORD + 1][KORD + 1];
    for (int n = 0; n <= KORD; ++n) {
        binom[n][0] = 1.0f;
        for (int k = 1; k <= n; ++k)
            binom[n][k] = (k == n) ? 1.0f : binom[n - 1][k - 1] + binom[n - 1][k];
        for (int k = n + 1; k <= KORD; ++k) binom[n][k] = 0.0f;
    }
    for (int m = 0; m <= KORD; ++m) {
        float s = 0.0f;
        for (int j = 0; j <= KORD; ++j) {
            float cj = 0.0f;
            for (int p = 0; p <= j && p <= m; ++p) {
                int q = m - p;
                if (q > KORD - j) continue;
                float t = binom[j][p] * binom[KORD - j][q];
                cj += (p & 1) ? -t : t;
            }
            s += binom[KORD][j] * T[j] * cj;
        }
        c[m] = s * (1.0f / 1024.0f);
    }
}

// ---------------- weight prep: transpose + bf16 ----------------

__global__ void k_prepw(const float* __restrict__ W1, const float* __restrict__ W2,
                        ushort_t* __restrict__ W1t, ushort_t* __restrict__ W2t) {
    int id = blockIdx.x * blockDim.x + threadIdx.x;
    if (id < HIDDEN * NFEAT) {
        int n = id / NFEAT, k = id % NFEAT;
        W1t[id] = f2bf(W1[(size_t)k * HIDDEN + n]);
    } else if (id < HIDDEN * NFEAT + NCLASS * HIDDEN) {
        int j = id - HIDDEN * NFEAT;
        int n = j / HIDDEN, k = j % HIDDEN;
        W2t[j] = f2bf(W2[(size_t)k * NCLASS + n]);
    }
}

// ---------------- GEMM1: h1 = relu(x @ W1 + b1), bf16 MFMA ----------------

__global__ __launch_bounds__(256) void gemm1(const float* __restrict__ x,
                                             const ushort_t* __restrict__ W1t,
                                             const float* __restrict__ b1,
                                             ushort_t* __restrict__ h1, int M) {
    __shared__ char smem[24576];
    char* As = smem;
    char* Bs = smem + 8192;
    const int t = threadIdx.x;
    const int m0 = blockIdx.x * 64;
    const int wid = t >> 6, lane = t & 63;
    const int wr = wid >> 1, wc = wid & 1;
    const int lm = lane & 15, lg = lane >> 4;

    f32x4 acc[2][4];
    #pragma unroll
    for (int i = 0; i < 2; ++i)
        #pragma unroll
        for (int j = 0; j < 4; ++j) acc[i][j] = (f32x4){0.f, 0.f, 0.f, 0.f};

    for (int k0 = 0; k0 < NFEAT; k0 += 64) {
        #pragma unroll
        for (int i = 0; i < 2; ++i) {
            int idx = t + i * 256;
            int r = idx >> 3, c8 = idx & 7;
            float4 v0 = make_float4(0.f, 0.f, 0.f, 0.f), v1 = v0;
            if (m0 + r < M) {
                const float* p = &x[(size_t)(m0 + r) * NFEAT + k0 + c8 * 8];
                v0 = *(const float4*)p;
                v1 = *(const float4*)(p + 4);
            }
            *(short8*)(As + r * 128 + ((c8 * 16) ^ ((r & 7) << 4))) = pack8(v0, v1);
        }
        #pragma unroll
        for (int i = 0; i < 4; ++i) {
            int idx = t + i * 256;
            int r = idx >> 3, c8 = idx & 7;
            short8 v = *(const short8*)&W1t[(size_t)r * NFEAT + k0 + c8 * 8];
            *(short8*)(Bs + r * 128 + ((c8 * 16) ^ ((r & 7) << 4))) = v;
        }
        __syncthreads();
        #pragma unroll
        for (int kk = 0; kk < 64; kk += 32) {
            int kb = (kk + lg * 8) * 2;
            short8 af[2], bfr[4];
            #pragma unroll
            for (int fi = 0; fi < 2; ++fi) {
                int m = wr * 32 + fi * 16 + lm;
                af[fi] = *(const short8*)(As + m * 128 + (kb ^ ((m & 7) << 4)));
            }
            #pragma unroll
            for (int fj = 0; fj < 4; ++fj) {
                int n = wc * 64 + fj * 16 + lm;
                bfr[fj] = *(const short8*)(Bs + n * 128 + (kb ^ ((n & 7) << 4)));
            }
            #pragma unroll
            for (int fi = 0; fi < 2; ++fi)
                #pragma unroll
                for (int fj = 0; fj < 4; ++fj)
                    acc[fi][fj] = __builtin_amdgcn_mfma_f32_16x16x32_bf16(
                        af[fi], bfr[fj], acc[fi][fj], 0, 0, 0);
        }
        __syncthreads();
    }

    ushort_t* Cs = (ushort_t*)smem;
    #pragma unroll
    for (int fi = 0; fi < 2; ++fi)
        #pragma unroll
        for (int fj = 0; fj < 4; ++fj) {
            int col = wc * 64 + fj * 16 + lm;
            float bb = b1[col];
            #pragma unroll
            for (int q = 0; q < 4; ++q) {
                int r = wr * 32 + fi * 16 + lg * 4 + q;
                float z = fmaxf(acc[fi][fj][q] + bb, 0.0f);
                Cs[r * 128 + col] = f2bf(z);
            }
        }
    __syncthreads();
    #pragma unroll
    for (int i = 0; i < 4; ++i) {
        int idx = t + i * 256;
        int r = idx >> 4, c8 = idx & 15;
        if (m0 + r < M)
            *(short8*)&h1[(size_t)(m0 + r) * HIDDEN + c8 * 8] =
                *(const short8*)&Cs[r * 128 + c8 * 8];
    }
}

// ---------------- GEMM2: h = h1 @ W2 + b2 ; emits hb, g0 = bf16(dinv*cK*h) ----

__global__ __launch_bounds__(256) void gemm2(const ushort_t* __restrict__ h1,
                                             const ushort_t* __restrict__ W2t,
                                             const float* __restrict__ b2,
                                             const float* __restrict__ dinv,
                                             const float* __restrict__ c,
                                             ushort_t* __restrict__ hb,
                                             ushort_t* __restrict__ g0, int M) {
    __shared__ char smem[49152];
    char* As = smem;
    char* Bs = smem + 32768;
    const int t = threadIdx.x;
    const int m0 = blockIdx.x * 128;
    const int wr = t >> 6, lane = t & 63;
    const int lm = lane & 15, lg = lane >> 4;

    #pragma unroll
    for (int i = 0; i < 8; ++i) {
        int idx = t + i * 256;
        int r = idx >> 4, c8 = idx & 15;
        short8 v = (short8){0, 0, 0, 0, 0, 0, 0, 0};
        if (m0 + r < M) v = *(const short8*)&h1[(size_t)(m0 + r) * HIDDEN + c8 * 8];
        *(short8*)(As + r * 256 + ((c8 * 16) ^ ((r & 7) << 4))) = v;
    }
    #pragma unroll
    for (int i = 0; i < 4; ++i) {
        int idx = t + i * 256;
        int r = idx >> 4, c8 = idx & 15;
        short8 v = *(const short8*)&W2t[(size_t)r * HIDDEN + c8 * 8];
        *(short8*)(Bs + r * 256 + ((c8 * 16) ^ ((r & 7) << 4))) = v;
    }
    __syncthreads();

    f32x4 acc[2][4];
    #pragma unroll
    for (int i = 0; i < 2; ++i)
        #pragma unroll
        for (int j = 0; j < 4; ++j) acc[i][j] = (f32x4){0.f, 0.f, 0.f, 0.f};

    #pragma unroll
    for (int kk = 0; kk < HIDDEN; kk += 32) {
        int kb = (kk + lg * 8) * 2;
        short8 af[2], bfr[4];
        #pragma unroll
        for (int fi = 0; fi < 2; ++fi) {
            int m = wr * 32 + fi * 16 + lm;
            af[fi] = *(const short8*)(As + m * 256 + (kb ^ ((m & 7) << 4)));
        }
        #pragma unroll
        for (int fj = 0; fj < 4; ++fj) {
            int n = fj * 16 + lm;
            bfr[fj] = *(const short8*)(Bs + n * 256 + (kb ^ ((n & 7) << 4)));
        }
        #pragma unroll
        for (int fi = 0; fi < 2; ++fi)
            #pragma unroll
            for (int fj = 0; fj < 4; ++fj)
                acc[fi][fj] = __builtin_amdgcn_mfma_f32_16x16x32_bf16(
                    af[fi], bfr[fj], acc[fi][fj], 0, 0, 0);
    }

    float cK = c[KORD];
    #pragma unroll
    for (int fi = 0; fi < 2; ++fi)
        #pragma unroll
        for (int q = 0; q < 4; ++q) {
            int r = m0 + wr * 32 + fi * 16 + lg * 4 + q;
            if (r < M) {
                float dv = dinv[r];
                #pragma unroll
                for (int fj = 0; fj < 4; ++fj) {
                    int col = fj * 16 + lm;
                    float z = acc[fi][fj][q] + b2[col];
                    size_t o = (size_t)r * NCLASS + col;
                    hb[o] = f2bf(z);
                    g0[o] = f2bf(dv * cK * z);
                }
            }
        }
}

// ---------------- Horner SpMV step: w = A*w_prev + c[cidx]*h ----------------
// quad scheme: 4 edges per wave-load; 16 lanes per edge, ushort4 (4 features) per lane.
// csr loads nontemporal: streamed once, keep L2 for gin gathers.

__global__ __launch_bounds__(256) void k_adj(const ushort_t* __restrict__ gin,
                                             const ushort_t* __restrict__ hb,
                                             const float* __restrict__ dinv,
                                             const int* __restrict__ row_ptr,
                                             const int* __restrict__ csr,
                                             const float* __restrict__ c, int cidx,
                                             ushort_t* __restrict__ gout,
                                             float* __restrict__ out, int last, int N) {
    int wid = blockIdx.x * 4 + (threadIdx.x >> 6);
    int lane = threadIdx.x & 63;
    if (wid >= N) return;
    const int g = lane >> 4;          // edge slot within quad
    const int f0 = (lane & 15) * 4;   // feature base
    int b = row_ptr[wid], e = row_ptr[wid + 1];

    float a0 = 0.f, a1 = 0.f, a2 = 0.f, a3 = 0.f;
    for (int i = b; i < e; i += 16) {
        #pragma unroll
        for (int u = 0; u < 4; ++u) {
            int ei = i + u * 4 + g;
            bool ok = ei < e;
            int s = ok ? __builtin_nontemporal_load(&csr[ei]) : 0;
            us4v v = *(const us4v*)&gin[(size_t)s * NCLASS + f0];
            float m = ok ? 1.0f : 0.0f;
            a0 += m * bf2f(v[0]);
            a1 += m * bf2f(v[1]);
            a2 += m * bf2f(v[2]);
            a3 += m * bf2f(v[3]);
        }
    }
    #pragma unroll
    for (int off = 16; off <= 32; off <<= 1) {
        a0 += __shfl_xor(a0, off);
        a1 += __shfl_xor(a1, off);
        a2 += __shfl_xor(a2, off);
        a3 += __shfl_xor(a3, off);
    }

    float dv = dinv[wid];
    float cc = c[cidx];
    size_t o = (size_t)wid * NCLASS + f0;
    us4v hv = *(const us4v*)&hb[o];
    float w0 = dv * a0 + cc * bf2f(hv[0]);
    float w1 = dv * a1 + cc * bf2f(hv[1]);
    float w2 = dv * a2 + cc * bf2f(hv[2]);
    float w3 = dv * a3 + cc * bf2f(hv[3]);

    if (!last) {
        if (g == 0) {
            us4v r;
            r[0] = f2bf(dv * w0);
            r[1] = f2bf(dv * w1);
            r[2] = f2bf(dv * w2);
            r[3] = f2bf(dv * w3);
            *(us4v*)&gout[o] = r;
        }
    } else {
        float mx = fmaxf(fmaxf(w0, w1), fmaxf(w2, w3));
        #pragma unroll
        for (int off = 8; off >= 1; off >>= 1) mx = fmaxf(mx, __shfl_xor(mx, off));
        float s = expf(w0 - mx) + expf(w1 - mx) + expf(w2 - mx) + expf(w3 - mx);
        #pragma unroll
        for (int off = 8; off >= 1; off >>= 1) s += __shfl_xor(s, off);
        float ls = logf(s);
        if (g == 0) {
            float4 r = make_float4(w0 - mx - ls, w1 - mx - ls, w2 - mx - ls, w3 - mx - ls);
            *(float4*)&out[o] = r;
        }
    }
}

// ---------------- launch ----------------

extern "C" void kernel_launch(void* const* d_in, const int* in_sizes, int n_in,
                              void* d_out, int out_size, void* d_ws, size_t ws_size,
                              hipStream_t stream) {
    const float* x = (const float*)d_in[0];
    const int* ei = (const int*)d_in[1];
    const float* W1 = (const float*)d_in[2];
    const float* b1 = (const float*)d_in[3];
    const float* W2 = (const float*)d_in[4];
    const float* b2 = (const float*)d_in[5];
    const float* temp = (const float*)d_in[6];

    const int N = in_sizes[0] / NFEAT;  // 100000
    const int E = in_sizes[1] / 2;      // 3200000
    const int* src = ei;
    const int* dst = ei + E;
    const int nbuck = (N + 63) >> 6;    // 1563

    float* out = (float*)d_out;
    float* temp_out = out + (size_t)N * NCLASS;

    char* ws = (char*)d_ws;
    size_t off = 0;
    auto alloc = [&](size_t bytes) {
        char* p = ws + off;
        off = (off + bytes + 255) & ~(size_t)255;
        return p;
    };
    ushort_t* h1 = (ushort_t*)alloc((size_t)N * HIDDEN * sizeof(ushort_t));  // 25.6MB
    ushort_t* hb = (ushort_t*)alloc((size_t)N * NCLASS * sizeof(ushort_t));
    ushort_t* gA = (ushort_t*)alloc((size_t)N * NCLASS * sizeof(ushort_t));
    ushort_t* gB = (ushort_t*)alloc((size_t)N * NCLASS * sizeof(ushort_t));
    float* dinv = (float*)alloc((size_t)N * sizeof(float));
    int* row_ptr = (int*)alloc((size_t)(N + 1) * sizeof(int));
    int* bhist = (int*)alloc((size_t)(2 * MAXBUCK) * sizeof(int));
    int* bstart = (int*)alloc((size_t)(MAXBUCK + 1) * sizeof(int));
    int* gpos = (int*)alloc((size_t)MAXBUCK * sizeof(int));
    int* sstart = (int*)alloc((size_t)(MAXBUCK + 1) * sizeof(int));
    int* spos = (int*)alloc((size_t)MAXBUCK * sizeof(int));
    int* csr = (int*)alloc((size_t)E * sizeof(int));
    ushort_t* W1t = (ushort_t*)alloc((size_t)HIDDEN * NFEAT * sizeof(ushort_t));
    ushort_t* W2t = (ushort_t*)alloc((size_t)NCLASS * HIDDEN * sizeof(ushort_t));
    float* c = (float*)alloc(64);
    (void)ws_size;

    // scratch aliased onto h1 (dead until gemm1): buf 12.8MB + sbuf 3.2MB < 25.6MB
    int* buf = (int*)h1;
    unsigned char* sbuf = (unsigned char*)h1 + (size_t)13 * 1024 * 1024;

    const int TB = 256;
    const int eg = (E + CH - 1) / CH;  // 391
    const int wgrid = (N + 3) / 4;

    hipMemsetAsync(bhist, 0, (size_t)(2 * MAXBUCK) * sizeof(int), stream);
    p0_hist<<<eg, TB, 0, stream>>>(src, dst, bhist, E, nbuck);
    p_scan<<<1, TB, 0, stream>>>(bhist, bstart, gpos, sstart, spos, nbuck, row_ptr, N, E);
    p1_scatter<<<eg, TB, 0, stream>>>(src, dst, gpos, spos, buf, sbuf, E, nbuck);
    p2_group<<<nbuck, TB, 0, stream>>>(buf, bstart, csr, row_ptr, N);
    p2b_deg<<<nbuck, TB, 0, stream>>>(sbuf, sstart, dinv, N);

    k_coef<<<1, 64, 0, stream>>>(temp, c, temp_out);
    k_prepw<<<(HIDDEN * NFEAT + NCLASS * HIDDEN + TB - 1) / TB, TB, 0, stream>>>(W1, W2, W1t, W2t);

    gemm1<<<(N + 63) / 64, TB, 0, stream>>>(x, W1t, b1, h1, N);
    gemm2<<<(N + 127) / 128, TB, 0, stream>>>(h1, W2t, b2, dinv, c, hb, gA, N);

    const ushort_t* gin = gA;
    ushort_t* gout = gB;
    for (int s = 1; s <= KORD; ++s) {
        int last = (s == KORD) ? 1 : 0;
        k_adj<<<wgrid, TB, 0, stream>>>(gin, hb, dinv, row_ptr, csr, c, KORD - s,
                                        gout, out, last, N);
        const ushort_t* tmp = gin;
        gin = gout;
        gout = (ushort_t*)tmp;
    }
}

// Round 7
// 842.278 us; speedup vs baseline: 1.4409x; 1.4409x over previous
//
#include <hip/hip_runtime.h>
#include <hip/hip_bf16.h>
#include <math.h>

// BernNet: h = relu(x@W1+b1)@W2+b2 ; out = sum_m c_m A^m h (Horner) ; log_softmax
// A = D^-1/2 Adj D^-1/2 (deg from src, scatter by dst). CSR(dst) built per launch
// via bucketed counting sort; deg via a parallel src-bucket byte sort (no per-edge
// global atomics). k_adj: octet gather scheme (8 lanes/edge, ushort8=16B/lane).
// NOTE: nontemporal loads on csr REGRESSED ~+195us total (bypassed L2/L3; round 6).

#define NFEAT 512
#define HIDDEN 128
#define NCLASS 64
#define KORD 10
#define MAXBUCK 1600   // LDS histogram capacity (N <= 102400)
#define CH 8192        // edges per block in bucket passes (391 blocks)

typedef unsigned short ushort_t;
typedef __attribute__((ext_vector_type(8))) short short8;
typedef __attribute__((ext_vector_type(4))) float f32x4;
typedef __attribute__((ext_vector_type(8))) unsigned short us8v;

static __device__ __forceinline__ float bf2f(ushort_t u) {
    return __uint_as_float(((unsigned)u) << 16);
}
static __device__ __forceinline__ ushort_t f2bf(float f) {
    __hip_bfloat16 h = __float2bfloat16(f);
    return *reinterpret_cast<ushort_t*>(&h);
}
static __device__ __forceinline__ short8 pack8(float4 a, float4 b) {
    short8 r;
    r[0] = (short)f2bf(a.x); r[1] = (short)f2bf(a.y);
    r[2] = (short)f2bf(a.z); r[3] = (short)f2bf(a.w);
    r[4] = (short)f2bf(b.x); r[5] = (short)f2bf(b.y);
    r[6] = (short)f2bf(b.z); r[7] = (short)f2bf(b.w);
    return r;
}

// ---------------- graph build: bucketed counting sort ----------------

__global__ __launch_bounds__(256) void p0_hist(const int* __restrict__ src,
                                               const int* __restrict__ dst,
                                               int* __restrict__ bhist,  // [2*MAXBUCK]
                                               int E, int nbuck) {
    __shared__ int hd[MAXBUCK];
    __shared__ int hs[MAXBUCK];
    for (int i = threadIdx.x; i < nbuck; i += 256) { hd[i] = 0; hs[i] = 0; }
    __syncthreads();
    int base = blockIdx.x * CH;
    int lim = min(base + CH, E);
    for (int e = base + threadIdx.x; e < lim; e += 256) {
        atomicAdd(&hd[dst[e] >> 6], 1);
        atomicAdd(&hs[src[e] >> 6], 1);
    }
    __syncthreads();
    for (int i = threadIdx.x; i < nbuck; i += 256) {
        int v = hd[i];
        if (v) atomicAdd(&bhist[i], v);
        int w = hs[i];
        if (w) atomicAdd(&bhist[MAXBUCK + i], w);
    }
}

__global__ __launch_bounds__(256) void p_scan(const int* __restrict__ bhist,
                                              int* __restrict__ bstart,
                                              int* __restrict__ gpos,
                                              int* __restrict__ sstart,
                                              int* __restrict__ spos, int nbuck,
                                              int* __restrict__ row_ptr, int N, int E) {
    __shared__ int ws[4];
    __shared__ int carry;
    int t = threadIdx.x, lane = t & 63, w = t >> 6;
    #pragma unroll
    for (int pass = 0; pass < 2; ++pass) {
        const int* in = bhist + pass * MAXBUCK;
        int* o1 = pass ? sstart : bstart;
        int* o2 = pass ? spos : gpos;
        if (t == 0) carry = 0;
        __syncthreads();
        for (int base = 0; base < nbuck; base += 256) {
            int i = base + t;
            int v = (i < nbuck) ? in[i] : 0;
            int s = v;
            #pragma unroll
            for (int off = 1; off < 64; off <<= 1) {
                int u = __shfl_up(s, off);
                if (lane >= off) s += u;
            }
            if (lane == 63) ws[w] = s;
            __syncthreads();
            int pre = 0;
            #pragma unroll
            for (int j = 0; j < 4; ++j)
                if (j < w) pre += ws[j];
            int excl = carry + pre + s - v;
            if (i < nbuck) {
                o1[i] = excl;
                o2[i] = excl;
            }
            __syncthreads();
            if (t == 255) carry += pre + s;
            __syncthreads();
        }
        if (t == 0) o1[nbuck] = E;
        __syncthreads();
    }
    if (t == 0) row_ptr[N] = E;
}

__global__ __launch_bounds__(256) void p1_scatter(const int* __restrict__ src,
                                                  const int* __restrict__ dst,
                                                  int* __restrict__ gpos,
                                                  int* __restrict__ spos,
                                                  int* __restrict__ buf,
                                                  unsigned char* __restrict__ sbuf,
                                                  int E, int nbuck) {
    __shared__ int hd[MAXBUCK];
    __shared__ int bd[MAXBUCK];
    __shared__ int hs[MAXBUCK];
    __shared__ int bs[MAXBUCK];
    for (int i = threadIdx.x; i < nbuck; i += 256) { hd[i] = 0; hs[i] = 0; }
    __syncthreads();
    int base = blockIdx.x * CH;
    int lim = min(base + CH, E);
    for (int e = base + threadIdx.x; e < lim; e += 256) {
        atomicAdd(&hd[dst[e] >> 6], 1);
        atomicAdd(&hs[src[e] >> 6], 1);
    }
    __syncthreads();
    for (int i = threadIdx.x; i < nbuck; i += 256) {
        int v = hd[i];
        bd[i] = v ? atomicAdd(&gpos[i], v) : 0;
        hd[i] = 0;
        int u = hs[i];
        bs[i] = u ? atomicAdd(&spos[i], u) : 0;
        hs[i] = 0;
    }
    __syncthreads();
    for (int e = base + threadIdx.x; e < lim; e += 256) {
        int d = dst[e], s = src[e];
        int bk = d >> 6;
        int off = atomicAdd(&hd[bk], 1);
        buf[bd[bk] + off] = s | ((d & 63) << 17);
        int sk = s >> 6;
        int off2 = atomicAdd(&hs[sk], 1);
        sbuf[bs[sk] + off2] = (unsigned char)(s & 63);
    }
}

__global__ __launch_bounds__(256) void p2_group(const int* __restrict__ buf,
                                                const int* __restrict__ bstart,
                                                int* __restrict__ csr,
                                                int* __restrict__ row_ptr, int N) {
    int bk = blockIdx.x;
    int s0 = bstart[bk], s1 = bstart[bk + 1];
    __shared__ int cnt[64];
    __shared__ int pos[64];
    int t = threadIdx.x;
    if (t < 64) cnt[t] = 0;
    __syncthreads();
    for (int i = s0 + t; i < s1; i += 256) atomicAdd(&cnt[buf[i] >> 17], 1);
    __syncthreads();
    if (t < 64) {
        int v = cnt[t], s = v;
        #pragma unroll
        for (int off = 1; off < 64; off <<= 1) {
            int u = __shfl_up(s, off);
            if (t >= off) s += u;
        }
        int excl = s - v;
        int node = bk * 64 + t;
        if (node < N) row_ptr[node] = s0 + excl;
        pos[t] = s0 + excl;
    }
    __syncthreads();
    for (int i = s0 + t; i < s1; i += 256) {
        int p = buf[i];
        int off = atomicAdd(&pos[p >> 17], 1);
        csr[off] = p & 0x1FFFF;
    }
}

__global__ __launch_bounds__(256) void p2b_deg(const unsigned char* __restrict__ sbuf,
                                               const int* __restrict__ sstart,
                                               float* __restrict__ dinv, int N) {
    int bk = blockIdx.x;
    int s0 = sstart[bk], s1 = sstart[bk + 1];
    __shared__ int cnt[64];
    int t = threadIdx.x;
    if (t < 64) cnt[t] = 0;
    __syncthreads();
    for (int i = s0 + t; i < s1; i += 256) atomicAdd(&cnt[sbuf[i]], 1);
    __syncthreads();
    if (t < 64) {
        int node = bk * 64 + t;
        if (node < N) {
            int d = cnt[t];
            dinv[node] = (d > 0) ? rsqrtf((float)d) : 0.0f;
        }
    }
}

// ---------------- Bernstein coefficients ----------------

__global__ void k_coef(const float* __restrict__ temp, float* __restrict__ c,
                       float* __restrict__ temp_out) {
    if (threadIdx.x != 0 || blockIdx.x != 0) return;
    float T[KORD + 1];
    #pragma unroll
    for (int j = 0; j <= KORD; ++j) {
        T[j] = fmaxf(temp[j], 0.0f);
        temp_out[j] = T[j];
    }
    float binom[KORD + 1][KORD + 1];
    for (int n = 0; n <= KORD; ++n) {
        binom[n][0] = 1.0f;
        for (int k = 1; k <= n; ++k)
            binom[n][k] = (k == n) ? 1.0f : binom[n - 1][k - 1] + binom[n - 1][k];
        for (int k = n + 1; k <= KORD; ++k) binom[n][k] = 0.0f;
    }
    for (int m = 0; m <= KORD; ++m) {
        float s = 0.0f;
        for (int j = 0; j <= KORD; ++j) {
            float cj = 0.0f;
            for (int p = 0; p <= j && p <= m; ++p) {
                int q = m - p;
                if (q > KORD - j) continue;
                float t = binom[j][p] * binom[KORD - j][q];
                cj += (p & 1) ? -t : t;
            }
            s += binom[KORD][j] * T[j] * cj;
        }
        c[m] = s * (1.0f / 1024.0f);
    }
}

// ---------------- weight prep: transpose + bf16 ----------------

__global__ void k_prepw(const float* __restrict__ W1, const float* __restrict__ W2,
                        ushort_t* __restrict__ W1t, ushort_t* __restrict__ W2t) {
    int id = blockIdx.x * blockDim.x + threadIdx.x;
    if (id < HIDDEN * NFEAT) {
        int n = id / NFEAT, k = id % NFEAT;
        W1t[id] = f2bf(W1[(size_t)k * HIDDEN + n]);
    } else if (id < HIDDEN * NFEAT + NCLASS * HIDDEN) {
        int j = id - HIDDEN * NFEAT;
        int n = j / HIDDEN, k = j % HIDDEN;
        W2t[j] = f2bf(W2[(size_t)k * NCLASS + n]);
    }
}

// ---------------- GEMM1: h1 = relu(x @ W1 + b1), bf16 MFMA ----------------

__global__ __launch_bounds__(256) void gemm1(const float* __restrict__ x,
                                             const ushort_t* __restrict__ W1t,
                                             const float* __restrict__ b1,
                                             ushort_t* __restrict__ h1, int M) {
    __shared__ char smem[24576];
    char* As = smem;
    char* Bs = smem + 8192;
    const int t = threadIdx.x;
    const int m0 = blockIdx.x * 64;
    const int wid = t >> 6, lane = t & 63;
    const int wr = wid >> 1, wc = wid & 1;
    const int lm = lane & 15, lg = lane >> 4;

    f32x4 acc[2][4];
    #pragma unroll
    for (int i = 0; i < 2; ++i)
        #pragma unroll
        for (int j = 0; j < 4; ++j) acc[i][j] = (f32x4){0.f, 0.f, 0.f, 0.f};

    for (int k0 = 0; k0 < NFEAT; k0 += 64) {
        #pragma unroll
        for (int i = 0; i < 2; ++i) {
            int idx = t + i * 256;
            int r = idx >> 3, c8 = idx & 7;
            float4 v0 = make_float4(0.f, 0.f, 0.f, 0.f), v1 = v0;
            if (m0 + r < M) {
                const float* p = &x[(size_t)(m0 + r) * NFEAT + k0 + c8 * 8];
                v0 = *(const float4*)p;
                v1 = *(const float4*)(p + 4);
            }
            *(short8*)(As + r * 128 + ((c8 * 16) ^ ((r & 7) << 4))) = pack8(v0, v1);
        }
        #pragma unroll
        for (int i = 0; i < 4; ++i) {
            int idx = t + i * 256;
            int r = idx >> 3, c8 = idx & 7;
            short8 v = *(const short8*)&W1t[(size_t)r * NFEAT + k0 + c8 * 8];
            *(short8*)(Bs + r * 128 + ((c8 * 16) ^ ((r & 7) << 4))) = v;
        }
        __syncthreads();
        #pragma unroll
        for (int kk = 0; kk < 64; kk += 32) {
            int kb = (kk + lg * 8) * 2;
            short8 af[2], bfr[4];
            #pragma unroll
            for (int fi = 0; fi < 2; ++fi) {
                int m = wr * 32 + fi * 16 + lm;
                af[fi] = *(const short8*)(As + m * 128 + (kb ^ ((m & 7) << 4)));
            }
            #pragma unroll
            for (int fj = 0; fj < 4; ++fj) {
                int n = wc * 64 + fj * 16 + lm;
                bfr[fj] = *(const short8*)(Bs + n * 128 + (kb ^ ((n & 7) << 4)));
            }
            #pragma unroll
            for (int fi = 0; fi < 2; ++fi)
                #pragma unroll
                for (int fj = 0; fj < 4; ++fj)
                    acc[fi][fj] = __builtin_amdgcn_mfma_f32_16x16x32_bf16(
                        af[fi], bfr[fj], acc[fi][fj], 0, 0, 0);
        }
        __syncthreads();
    }

    ushort_t* Cs = (ushort_t*)smem;
    #pragma unroll
    for (int fi = 0; fi < 2; ++fi)
        #pragma unroll
        for (int fj = 0; fj < 4; ++fj) {
            int col = wc * 64 + fj * 16 + lm;
            float bb = b1[col];
            #pragma unroll
            for (int q = 0; q < 4; ++q) {
                int r = wr * 32 + fi * 16 + lg * 4 + q;
                float z = fmaxf(acc[fi][fj][q] + bb, 0.0f);
                Cs[r * 128 + col] = f2bf(z);
            }
        }
    __syncthreads();
    #pragma unroll
    for (int i = 0; i < 4; ++i) {
        int idx = t + i * 256;
        int r = idx >> 4, c8 = idx & 15;
        if (m0 + r < M)
            *(short8*)&h1[(size_t)(m0 + r) * HIDDEN + c8 * 8] =
                *(const short8*)&Cs[r * 128 + c8 * 8];
    }
}

// ---------------- GEMM2: h = h1 @ W2 + b2 ; emits hb, g0 = bf16(dinv*cK*h) ----

__global__ __launch_bounds__(256) void gemm2(const ushort_t* __restrict__ h1,
                                             const ushort_t* __restrict__ W2t,
                                             const float* __restrict__ b2,
                                             const float* __restrict__ dinv,
                                             const float* __restrict__ c,
                                             ushort_t* __restrict__ hb,
                                             ushort_t* __restrict__ g0, int M) {
    __shared__ char smem[49152];
    char* As = smem;
    char* Bs = smem + 32768;
    const int t = threadIdx.x;
    const int m0 = blockIdx.x * 128;
    const int wr = t >> 6, lane = t & 63;
    const int lm = lane & 15, lg = lane >> 4;

    #pragma unroll
    for (int i = 0; i < 8; ++i) {
        int idx = t + i * 256;
        int r = idx >> 4, c8 = idx & 15;
        short8 v = (short8){0, 0, 0, 0, 0, 0, 0, 0};
        if (m0 + r < M) v = *(const short8*)&h1[(size_t)(m0 + r) * HIDDEN + c8 * 8];
        *(short8*)(As + r * 256 + ((c8 * 16) ^ ((r & 7) << 4))) = v;
    }
    #pragma unroll
    for (int i = 0; i < 4; ++i) {
        int idx = t + i * 256;
        int r = idx >> 4, c8 = idx & 15;
        short8 v = *(const short8*)&W2t[(size_t)r * HIDDEN + c8 * 8];
        *(short8*)(Bs + r * 256 + ((c8 * 16) ^ ((r & 7) << 4))) = v;
    }
    __syncthreads();

    f32x4 acc[2][4];
    #pragma unroll
    for (int i = 0; i < 2; ++i)
        #pragma unroll
        for (int j = 0; j < 4; ++j) acc[i][j] = (f32x4){0.f, 0.f, 0.f, 0.f};

    #pragma unroll
    for (int kk = 0; kk < HIDDEN; kk += 32) {
        int kb = (kk + lg * 8) * 2;
        short8 af[2], bfr[4];
        #pragma unroll
        for (int fi = 0; fi < 2; ++fi) {
            int m = wr * 32 + fi * 16 + lm;
            af[fi] = *(const short8*)(As + m * 256 + (kb ^ ((m & 7) << 4)));
        }
        #pragma unroll
        for (int fj = 0; fj < 4; ++fj) {
            int n = fj * 16 + lm;
            bfr[fj] = *(const short8*)(Bs + n * 256 + (kb ^ ((n & 7) << 4)));
        }
        #pragma unroll
        for (int fi = 0; fi < 2; ++fi)
            #pragma unroll
            for (int fj = 0; fj < 4; ++fj)
                acc[fi][fj] = __builtin_amdgcn_mfma_f32_16x16x32_bf16(
                    af[fi], bfr[fj], acc[fi][fj], 0, 0, 0);
    }

    float cK = c[KORD];
    #pragma unroll
    for (int fi = 0; fi < 2; ++fi)
        #pragma unroll
        for (int q = 0; q < 4; ++q) {
            int r = m0 + wr * 32 + fi * 16 + lg * 4 + q;
            if (r < M) {
                float dv = dinv[r];
                #pragma unroll
                for (int fj = 0; fj < 4; ++fj) {
                    int col = fj * 16 + lm;
                    float z = acc[fi][fj][q] + b2[col];
                    size_t o = (size_t)r * NCLASS + col;
                    hb[o] = f2bf(z);
                    g0[o] = f2bf(dv * cK * z);
                }
            }
        }
}

// ---------------- Horner SpMV step: w = A*w_prev + c[cidx]*h ----------------
// octet scheme: 8 edges per wave-load; 8 lanes per edge, ushort8 (8 features, 16B).

__global__ __launch_bounds__(256) void k_adj(const ushort_t* __restrict__ gin,
                                             const ushort_t* __restrict__ hb,
                                             const float* __restrict__ dinv,
                                             const int* __restrict__ row_ptr,
                                             const int* __restrict__ csr,
                                             const float* __restrict__ c, int cidx,
                                             ushort_t* __restrict__ gout,
                                             float* __restrict__ out, int last, int N) {
    int wid = blockIdx.x * 4 + (threadIdx.x >> 6);
    int lane = threadIdx.x & 63;
    if (wid >= N) return;
    const int g = lane >> 3;         // edge slot within octet (0..7)
    const int f0 = (lane & 7) * 8;   // feature base
    int b = row_ptr[wid], e = row_ptr[wid + 1];

    float a[8] = {0.f, 0.f, 0.f, 0.f, 0.f, 0.f, 0.f, 0.f};
    for (int i = b; i < e; i += 32) {
        #pragma unroll
        for (int u = 0; u < 4; ++u) {
            int ei = i + u * 8 + g;
            bool ok = ei < e;
            int s = ok ? csr[ei] : 0;
            us8v v = *(const us8v*)&gin[(size_t)s * NCLASS + f0];
            float m = ok ? 1.0f : 0.0f;
            #pragma unroll
            for (int q = 0; q < 8; ++q) a[q] += m * bf2f(v[q]);
        }
    }
    // combine the 8 edge-groups (lanes with equal lane&7)
    #pragma unroll
    for (int off = 8; off <= 32; off <<= 1)
        #pragma unroll
        for (int q = 0; q < 8; ++q) a[q] += __shfl_xor(a[q], off);

    float dv = dinv[wid];
    float cc = c[cidx];
    size_t o = (size_t)wid * NCLASS + f0;
    us8v hv = *(const us8v*)&hb[o];
    float w[8];
    #pragma unroll
    for (int q = 0; q < 8; ++q) w[q] = dv * a[q] + cc * bf2f(hv[q]);

    if (!last) {
        if (g == 0) {
            us8v r;
            #pragma unroll
            for (int q = 0; q < 8; ++q) r[q] = f2bf(dv * w[q]);
            *(us8v*)&gout[o] = r;
        }
    } else {
        float mx = w[0];
        #pragma unroll
        for (int q = 1; q < 8; ++q) mx = fmaxf(mx, w[q]);
        #pragma unroll
        for (int off = 4; off >= 1; off >>= 1) mx = fmaxf(mx, __shfl_xor(mx, off));
        float s = 0.f;
        #pragma unroll
        for (int q = 0; q < 8; ++q) s += expf(w[q] - mx);
        #pragma unroll
        for (int off = 4; off >= 1; off >>= 1) s += __shfl_xor(s, off);
        float ls = logf(s);
        if (g == 0) {
            float4 r0 = make_float4(w[0] - mx - ls, w[1] - mx - ls,
                                    w[2] - mx - ls, w[3] - mx - ls);
            float4 r1 = make_float4(w[4] - mx - ls, w[5] - mx - ls,
                                    w[6] - mx - ls, w[7] - mx - ls);
            *(float4*)&out[o] = r0;
            *(float4*)&out[o + 4] = r1;
        }
    }
}

// ---------------- launch ----------------

extern "C" void kernel_launch(void* const* d_in, const int* in_sizes, int n_in,
                              void* d_out, int out_size, void* d_ws, size_t ws_size,
                              hipStream_t stream) {
    const float* x = (const float*)d_in[0];
    const int* ei = (const int*)d_in[1];
    const float* W1 = (const float*)d_in[2];
    const float* b1 = (const float*)d_in[3];
    const float* W2 = (const float*)d_in[4];
    const float* b2 = (const float*)d_in[5];
    const float* temp = (const float*)d_in[6];

    const int N = in_sizes[0] / NFEAT;  // 100000
    const int E = in_sizes[1] / 2;      // 3200000
    const int* src = ei;
    const int* dst = ei + E;
    const int nbuck = (N + 63) >> 6;    // 1563

    float* out = (float*)d_out;
    float* temp_out = out + (size_t)N * NCLASS;

    char* ws = (char*)d_ws;
    size_t off = 0;
    auto alloc = [&](size_t bytes) {
        char* p = ws + off;
        off = (off + bytes + 255) & ~(size_t)255;
        return p;
    };
    ushort_t* h1 = (ushort_t*)alloc((size_t)N * HIDDEN * sizeof(ushort_t));  // 25.6MB
    ushort_t* hb = (ushort_t*)alloc((size_t)N * NCLASS * sizeof(ushort_t));
    ushort_t* gA = (ushort_t*)alloc((size_t)N * NCLASS * sizeof(ushort_t));
    ushort_t* gB = (ushort_t*)alloc((size_t)N * NCLASS * sizeof(ushort_t));
    float* dinv = (float*)alloc((size_t)N * sizeof(float));
    int* row_ptr = (int*)alloc((size_t)(N + 1) * sizeof(int));
    int* bhist = (int*)alloc((size_t)(2 * MAXBUCK) * sizeof(int));
    int* bstart = (int*)alloc((size_t)(MAXBUCK + 1) * sizeof(int));
    int* gpos = (int*)alloc((size_t)MAXBUCK * sizeof(int));
    int* sstart = (int*)alloc((size_t)(MAXBUCK + 1) * sizeof(int));
    int* spos = (int*)alloc((size_t)MAXBUCK * sizeof(int));
    int* csr = (int*)alloc((size_t)E * sizeof(int));
    ushort_t* W1t = (ushort_t*)alloc((size_t)HIDDEN * NFEAT * sizeof(ushort_t));
    ushort_t* W2t = (ushort_t*)alloc((size_t)NCLASS * HIDDEN * sizeof(ushort_t));
    float* c = (float*)alloc(64);
    (void)ws_size;

    // scratch aliased onto h1 (dead until gemm1): buf 12.8MB + sbuf 3.2MB < 25.6MB
    int* buf = (int*)h1;
    unsigned char* sbuf = (unsigned char*)h1 + (size_t)13 * 1024 * 1024;

    const int TB = 256;
    const int eg = (E + CH - 1) / CH;  // 391
    const int wgrid = (N + 3) / 4;

    hipMemsetAsync(bhist, 0, (size_t)(2 * MAXBUCK) * sizeof(int), stream);
    p0_hist<<<eg, TB, 0, stream>>>(src, dst, bhist, E, nbuck);
    p_scan<<<1, TB, 0, stream>>>(bhist, bstart, gpos, sstart, spos, nbuck, row_ptr, N, E);
    p1_scatter<<<eg, TB, 0, stream>>>(src, dst, gpos, spos, buf, sbuf, E, nbuck);
    p2_group<<<nbuck, TB, 0, stream>>>(buf, bstart, csr, row_ptr, N);
    p2b_deg<<<nbuck, TB, 0, stream>>>(sbuf, sstart, dinv, N);

    k_coef<<<1, 64, 0, stream>>>(temp, c, temp_out);
    k_prepw<<<(HIDDEN * NFEAT + NCLASS * HIDDEN + TB - 1) / TB, TB, 0, stream>>>(W1, W2, W1t, W2t);

    gemm1<<<(N + 63) / 64, TB, 0, stream>>>(x, W1t, b1, h1, N);
    gemm2<<<(N + 127) / 128, TB, 0, stream>>>(h1, W2t, b2, dinv, c, hb, gA, N);

    const ushort_t* gin = gA;
    ushort_t* gout = gB;
    for (int s = 1; s <= KORD; ++s) {
        int last = (s == KORD) ? 1 : 0;
        k_adj<<<wgrid, TB, 0, stream>>>(gin, hb, dinv, row_ptr, csr, c, KORD - s,
                                        gout, out, last, N);
        const ushort_t* tmp = gin;
        gin = gout;
        gout = (ushort_t*)tmp;
    }
}